// Round 1
// baseline (4853.238 us; speedup 1.0000x reference)
//
#include <hip/hip_runtime.h>

#define NN 100000
#define EMBD 64
#define HIDD 128
#define OUTD 64
#define NE 1600000
#define BN_EPS 1e-5f

// ---------------- gather: x0 = emb_table[node_ids] ----------------
__global__ void gather_kernel(const int* __restrict__ ids,
                              const float* __restrict__ emb,
                              float* __restrict__ x0) {
    int tid = blockIdx.x * 256 + threadIdx.x;       // NN*16 threads
    int i = tid >> 4, q = tid & 15;
    if (i >= NN) return;
    int nid = ids[i];
    float4 v = ((const float4*)(emb + (size_t)nid * EMBD))[q];
    ((float4*)(x0 + (size_t)i * EMBD))[q] = v;
}

// ---------------- scatter: agg[dst] += x[src], C channels ----------------
template<int C>
__global__ void scatter_kernel(const float* __restrict__ x,
                               const int* __restrict__ src,
                               const int* __restrict__ dst,
                               float* __restrict__ agg) {
    constexpr int QP = C / 4;                        // float4 chunks per row
    int tid = blockIdx.x * 256 + threadIdx.x;        // NE*QP threads
    int e = tid / QP;
    int q = tid % QP;                                // QP is pow2 -> shifts
    if (e >= NE) return;
    int s = src[e], d = dst[e];
    float4 v = ((const float4*)(x + (size_t)s * C))[q];
    float* ap = agg + (size_t)d * C + q * 4;
    atomicAdd(ap + 0, v.x);
    atomicAdd(ap + 1, v.y);
    atomicAdd(ap + 2, v.z);
    atomicAdd(ap + 3, v.w);
}

// ---------------- fold BN (+ linear bias) into per-channel scale/shift ----------------
// y = (h + b1 - mean) * gamma*rsqrt(var+eps) + beta  ==  h*S + T
__global__ void prep_bn(const float* __restrict__ c1_b1, const float* __restrict__ c1_g,
                        const float* __restrict__ c1_be, const float* __restrict__ c1_m,
                        const float* __restrict__ c1_v,
                        const float* __restrict__ c2_b1, const float* __restrict__ c2_g,
                        const float* __restrict__ c2_be, const float* __restrict__ c2_m,
                        const float* __restrict__ c2_v,
                        float* __restrict__ ST) {
    int t = threadIdx.x;                             // 128 threads
    float s1 = c1_g[t] * rsqrtf(c1_v[t] + BN_EPS);
    ST[t]       = s1;
    ST[128 + t] = (c1_b1[t] - c1_m[t]) * s1 + c1_be[t];
    float s2 = c2_g[t] * rsqrtf(c2_v[t] + BN_EPS);
    ST[256 + t] = s2;
    ST[384 + t] = (c2_b1[t] - c2_m[t]) * s2 + c2_be[t];
}

// ---------------- fused linear(+add)(+BN)(+ReLU): thread-per-node ----------------
// Weights indexed uniformly (no tid dependence) -> scalar s_load broadcasts;
// inner loop is v_fmac_f32 acc, s_w, v_x at full VALU rate.
template<int IN, int OUT, bool ADD2, bool BN, bool RELU>
__global__ __launch_bounds__(256) void layer_kernel(
        const float* __restrict__ A, const float* __restrict__ B,
        const float* __restrict__ W, const float* __restrict__ bias,
        const float* __restrict__ S, const float* __restrict__ T,
        float* __restrict__ Y) {
    int n = blockIdx.x * 256 + threadIdx.x;
    if (n >= NN) return;
    const float4* rowA = (const float4*)(A + (size_t)n * IN);
    const float4* rowB = (const float4*)(B + (size_t)n * IN);
    constexpr int CG = 32;                           // channels per sweep
    for (int cg = 0; cg < OUT; cg += CG) {
        float acc[CG];
#pragma unroll
        for (int j = 0; j < CG; ++j) acc[j] = 0.f;
        for (int k4 = 0; k4 < IN / 4; ++k4) {
            float4 a = rowA[k4];
            if constexpr (ADD2) {
                float4 b = rowB[k4];
                a.x += b.x; a.y += b.y; a.z += b.z; a.w += b.w;
            }
            const float* wrow = W + (size_t)(k4 * 4) * OUT + cg;  // uniform
#pragma unroll
            for (int kk = 0; kk < 4; ++kk) {
                float xk = (kk == 0) ? a.x : (kk == 1) ? a.y : (kk == 2) ? a.z : a.w;
#pragma unroll
                for (int j = 0; j < CG; ++j)
                    acc[j] += xk * wrow[kk * OUT + j];
            }
        }
#pragma unroll
        for (int j = 0; j < CG; ++j) {
            int c = cg + j;
            float y = acc[j];
            if constexpr (BN)  y = y * S[c] + T[c];
            else               y = y + bias[c];
            if constexpr (RELU) y = fmaxf(y, 0.f);
            Y[(size_t)n * OUT + c] = y;
        }
    }
}

extern "C" void kernel_launch(void* const* d_in, const int* in_sizes, int n_in,
                              void* d_out, int out_size, void* d_ws, size_t ws_size,
                              hipStream_t stream) {
    const int*   node_ids = (const int*)d_in[0];
    const int*   src      = (const int*)d_in[1];          // edge_index[0]
    const int*   dst      = ((const int*)d_in[1]) + NE;   // edge_index[1]
    const float* emb      = (const float*)d_in[2];
    const float* c1_W1 = (const float*)d_in[3];
    const float* c1_b1 = (const float*)d_in[4];
    const float* c1_g  = (const float*)d_in[5];
    const float* c1_be = (const float*)d_in[6];
    const float* c1_m  = (const float*)d_in[7];
    const float* c1_v  = (const float*)d_in[8];
    const float* c1_W2 = (const float*)d_in[9];
    const float* c1_b2 = (const float*)d_in[10];
    const float* c2_W1 = (const float*)d_in[11];
    const float* c2_b1 = (const float*)d_in[12];
    const float* c2_g  = (const float*)d_in[13];
    const float* c2_be = (const float*)d_in[14];
    const float* c2_m  = (const float*)d_in[15];
    const float* c2_v  = (const float*)d_in[16];
    const float* c2_W2 = (const float*)d_in[17];
    const float* c2_b2 = (const float*)d_in[18];
    const float* out_W = (const float*)d_in[19];
    const float* out_b = (const float*)d_in[20];
    float* out = (float*)d_out;

    // workspace layout (float offsets)
    float* ws = (float*)d_ws;
    const size_t NE64  = (size_t)NN * 64;    // 6.4M floats
    const size_t NE128 = (size_t)NN * 128;   // 12.8M floats
    float* x0   = ws;                        // [0,      6.4M)
    float* agg1 = ws + NE64;                 // [6.4M,  12.8M)
    float* h1   = ws + 2 * NE64;             // [12.8M, 25.6M)
    float* x1   = ws + 2 * NE64 + NE128;     // [25.6M, 38.4M)
    float* agg2 = ws;                        // reuse [0, 12.8M)  (x0,agg1 dead)
    float* h2   = ws + 2 * NE64;             // reuse h1 slot
    float* x2   = ws;                        // reuse agg2 slot
    float* ST   = ws + 2 * NE64 + 2 * NE128; // +512 floats
    float* S1 = ST, *T1 = ST + 128, *S2 = ST + 256, *T2 = ST + 384;

    // conv1
    hipMemsetAsync(agg1, 0, NE64 * sizeof(float), stream);
    gather_kernel<<<(NN * 16 + 255) / 256, 256, 0, stream>>>(node_ids, emb, x0);
    prep_bn<<<1, 128, 0, stream>>>(c1_b1, c1_g, c1_be, c1_m, c1_v,
                                   c2_b1, c2_g, c2_be, c2_m, c2_v, ST);
    scatter_kernel<64><<<(NE * 16 + 255) / 256, 256, 0, stream>>>(x0, src, dst, agg1);
    layer_kernel<64, 128, true, true, true><<<(NN + 255) / 256, 256, 0, stream>>>(
        x0, agg1, c1_W1, nullptr, S1, T1, h1);
    layer_kernel<128, 128, false, false, true><<<(NN + 255) / 256, 256, 0, stream>>>(
        h1, h1, c1_W2, c1_b2, nullptr, nullptr, x1);

    // conv2
    hipMemsetAsync(agg2, 0, NE128 * sizeof(float), stream);
    scatter_kernel<128><<<(NE * 32 + 255) / 256, 256, 0, stream>>>(x1, src, dst, agg2);
    layer_kernel<128, 128, true, true, true><<<(NN + 255) / 256, 256, 0, stream>>>(
        x1, agg2, c2_W1, nullptr, S2, T2, h2);
    layer_kernel<128, 128, false, false, true><<<(NN + 255) / 256, 256, 0, stream>>>(
        h2, h2, c2_W2, c2_b2, nullptr, nullptr, x2);

    // output projection
    layer_kernel<128, 64, false, false, false><<<(NN + 255) / 256, 256, 0, stream>>>(
        x2, x2, out_W, out_b, nullptr, nullptr, out);
}

// Round 12
// 1180.803 us; speedup vs baseline: 4.1101x; 4.1101x over previous
//
#include <hip/hip_runtime.h>

#define NN 100000
#define EMBD 64
#define HIDD 128
#define OUTD 64
#define NE 1600000
#define BN_EPS 1e-5f
#define SCAN_B 1024
#define SCAN_NB ((NN + SCAN_B - 1) / SCAN_B)   // 98

// ---------------- gather: x0 = emb_table[node_ids] ----------------
__global__ void gather_kernel(const int* __restrict__ ids,
                              const float* __restrict__ emb,
                              float* __restrict__ x0) {
    int tid = blockIdx.x * 256 + threadIdx.x;       // NN*16 threads
    int i = tid >> 4, q = tid & 15;
    if (i >= NN) return;
    int nid = ids[i];
    float4 v = ((const float4*)(emb + (size_t)nid * EMBD))[q];
    ((float4*)(x0 + (size_t)i * EMBD))[q] = v;
}

// ---------------- CSR build ----------------
__global__ void hist_kernel(const int* __restrict__ dst, int* __restrict__ deg) {
    int e = blockIdx.x * 256 + threadIdx.x;
    if (e < NE) atomicAdd(&deg[dst[e]], 1);
}

__global__ void scan1_kernel(const int* __restrict__ deg, int* __restrict__ rowstart,
                             int* __restrict__ blocksum) {
    __shared__ int s[SCAN_B];
    int t = threadIdx.x, i = blockIdx.x * SCAN_B + t;
    int v = (i < NN) ? deg[i] : 0;
    s[t] = v;
    __syncthreads();
    for (int off = 1; off < SCAN_B; off <<= 1) {
        int a = (t >= off) ? s[t - off] : 0;
        __syncthreads();
        s[t] += a;
        __syncthreads();
    }
    if (i < NN) rowstart[i] = s[t] - v;              // exclusive within block
    if (t == SCAN_B - 1) blocksum[blockIdx.x] = s[t];
}

__global__ void scan2_kernel(int* __restrict__ blocksum) {
    if (threadIdx.x == 0 && blockIdx.x == 0) {
        int run = 0;
        for (int i = 0; i < SCAN_NB; ++i) { int t = blocksum[i]; blocksum[i] = run; run += t; }
    }
}

__global__ void scan3_kernel(int* __restrict__ rowstart, const int* __restrict__ blocksum,
                             int* __restrict__ cursor) {
    int t = threadIdx.x, i = blockIdx.x * SCAN_B + t;
    if (i < NN) {
        int r = rowstart[i] + blocksum[blockIdx.x];
        rowstart[i] = r;
        cursor[i] = r;
    }
    if (i == 0) rowstart[NN] = NE;
}

__global__ void fill_kernel(const int* __restrict__ src, const int* __restrict__ dst,
                            int* __restrict__ cursor, int* __restrict__ adj) {
    int e = blockIdx.x * 256 + threadIdx.x;
    if (e >= NE) return;
    int d = dst[e];
    int p = atomicAdd(&cursor[d], 1);
    adj[p] = src[e];
}

// ---------------- aggregate: agg[i] = sum_{j in adj[rs:re)} x[j], C channels ----------------
template<int C>
__global__ __launch_bounds__(256) void agg_kernel(const float* __restrict__ x,
                                                  const int* __restrict__ rowstart,
                                                  const int* __restrict__ adj,
                                                  float* __restrict__ agg) {
    constexpr int QP = C / 4;
    int tid = blockIdx.x * 256 + threadIdx.x;        // NN*QP threads
    int i = tid / QP, q = tid % QP;
    if (i >= NN) return;
    int rs = rowstart[i], re = rowstart[i + 1];
    float4 acc = {0.f, 0.f, 0.f, 0.f};
    for (int j = rs; j < re; ++j) {
        int s = adj[j];                              // broadcast within QP group
        float4 v = ((const float4*)(x + (size_t)s * C))[q];
        acc.x += v.x; acc.y += v.y; acc.z += v.z; acc.w += v.w;
    }
    ((float4*)(agg + (size_t)i * C))[q] = acc;
}

// ---------------- fold BN (+ linear bias) into per-channel scale/shift ----------------
__global__ void prep_bn(const float* __restrict__ c1_b1, const float* __restrict__ c1_g,
                        const float* __restrict__ c1_be, const float* __restrict__ c1_m,
                        const float* __restrict__ c1_v,
                        const float* __restrict__ c2_b1, const float* __restrict__ c2_g,
                        const float* __restrict__ c2_be, const float* __restrict__ c2_m,
                        const float* __restrict__ c2_v,
                        float* __restrict__ ST) {
    int t = threadIdx.x;                             // 128 threads
    float s1 = c1_g[t] * rsqrtf(c1_v[t] + BN_EPS);
    ST[t]       = s1;
    ST[128 + t] = (c1_b1[t] - c1_m[t]) * s1 + c1_be[t];
    float s2 = c2_g[t] * rsqrtf(c2_v[t] + BN_EPS);
    ST[256 + t] = s2;
    ST[384 + t] = (c2_b1[t] - c2_m[t]) * s2 + c2_be[t];
}

// ---------------- fused linear(+add)(+BN)(+ReLU): thread-per-node ----------------
template<int IN, int OUT, bool ADD2, bool BN, bool RELU>
__global__ __launch_bounds__(256) void layer_kernel(
        const float* __restrict__ A, const float* __restrict__ B,
        const float* __restrict__ W, const float* __restrict__ bias,
        const float* __restrict__ S, const float* __restrict__ T,
        float* __restrict__ Y) {
    int n = blockIdx.x * 256 + threadIdx.x;
    if (n >= NN) return;
    const float4* rowA = (const float4*)(A + (size_t)n * IN);
    const float4* rowB = (const float4*)(B + (size_t)n * IN);
    constexpr int CG = 32;                           // channels per sweep
    for (int cg = 0; cg < OUT; cg += CG) {
        float acc[CG];
#pragma unroll
        for (int j = 0; j < CG; ++j) acc[j] = 0.f;
        for (int k4 = 0; k4 < IN / 4; ++k4) {
            float4 a = rowA[k4];
            if constexpr (ADD2) {
                float4 b = rowB[k4];
                a.x += b.x; a.y += b.y; a.z += b.z; a.w += b.w;
            }
            const float* wrow = W + (size_t)(k4 * 4) * OUT + cg;  // uniform -> s_load
#pragma unroll
            for (int kk = 0; kk < 4; ++kk) {
                float xk = (kk == 0) ? a.x : (kk == 1) ? a.y : (kk == 2) ? a.z : a.w;
#pragma unroll
                for (int j = 0; j < CG; ++j)
                    acc[j] += xk * wrow[kk * OUT + j];
            }
        }
#pragma unroll
        for (int j = 0; j < CG; ++j) {
            int c = cg + j;
            float y = acc[j];
            if constexpr (BN)  y = y * S[c] + T[c];
            else               y = y + bias[c];
            if constexpr (RELU) y = fmaxf(y, 0.f);
            Y[(size_t)n * OUT + c] = y;
        }
    }
}

extern "C" void kernel_launch(void* const* d_in, const int* in_sizes, int n_in,
                              void* d_out, int out_size, void* d_ws, size_t ws_size,
                              hipStream_t stream) {
    const int*   node_ids = (const int*)d_in[0];
    const int*   src      = (const int*)d_in[1];          // edge_index[0]
    const int*   dst      = ((const int*)d_in[1]) + NE;   // edge_index[1]
    const float* emb      = (const float*)d_in[2];
    const float* c1_W1 = (const float*)d_in[3];
    const float* c1_b1 = (const float*)d_in[4];
    const float* c1_g  = (const float*)d_in[5];
    const float* c1_be = (const float*)d_in[6];
    const float* c1_m  = (const float*)d_in[7];
    const float* c1_v  = (const float*)d_in[8];
    const float* c1_W2 = (const float*)d_in[9];
    const float* c1_b2 = (const float*)d_in[10];
    const float* c2_W1 = (const float*)d_in[11];
    const float* c2_b1 = (const float*)d_in[12];
    const float* c2_g  = (const float*)d_in[13];
    const float* c2_be = (const float*)d_in[14];
    const float* c2_m  = (const float*)d_in[15];
    const float* c2_v  = (const float*)d_in[16];
    const float* c2_W2 = (const float*)d_in[17];
    const float* c2_b2 = (const float*)d_in[18];
    const float* out_W = (const float*)d_in[19];
    const float* out_b = (const float*)d_in[20];
    float* out = (float*)d_out;

    // ---- workspace layout (4-byte words); peak footprint == round-0's proven 38.4M+512 ----
    float* ws = (float*)d_ws;
    const size_t W64  = (size_t)NN * 64;     // 6.4M
    const size_t W128 = (size_t)NN * 128;    // 12.8M
    float* x0   = ws;                        // [0, 6.4M)        live: gather..layer1
    float* agg1 = ws + W64;                  // [6.4M, 12.8M)    live: agg1..layer1
    float* h1   = ws + 2 * W64;              // [12.8M, 25.6M)   live: layer1..layer2
    float* x1   = ws;                        // [0, 12.8M)       live: layer2..layer3 (x0,agg1 dead)
    float* agg2 = ws + 2 * W64;              // [12.8M, 25.6M)   live: agg2..layer3 (h1 dead)
    float* h2   = ws + 2 * W64 + W128;       // [25.6M, 38.4M)   live: layer3..layer4
    float* x2   = ws;                        // [0, 12.8M)       live: layer4..out (x1 dead)
    // CSR block shares h2's region; CSR dead before h2 is written (layer3)
    int* rowstart = (int*)(ws + 2 * W64 + W128);       // NN+1 ints
    int* cursor   = rowstart + (NN + 1);               // NN ints (deg during hist)
    int* blocksum = cursor + NN;                       // SCAN_NB ints
    int* adj      = blocksum + 128;                    // NE ints  (total CSR ≈ 7.2 MB)
    float* ST = ws + 2 * W64 + 2 * W128;               // [38.4M, 38.4M+512)
    float* S1 = ST, *T1 = ST + 128, *S2 = ST + 256, *T2 = ST + 384;

    // ---- CSR build ----
    hipMemsetAsync(cursor, 0, NN * sizeof(int), stream);
    hist_kernel<<<(NE + 255) / 256, 256, 0, stream>>>(dst, cursor);
    scan1_kernel<<<SCAN_NB, SCAN_B, 0, stream>>>(cursor, rowstart, blocksum);
    scan2_kernel<<<1, 64, 0, stream>>>(blocksum);
    scan3_kernel<<<SCAN_NB, SCAN_B, 0, stream>>>(rowstart, blocksum, cursor);
    fill_kernel<<<(NE + 255) / 256, 256, 0, stream>>>(src, dst, cursor, adj);

    // ---- conv1 ----
    gather_kernel<<<(NN * 16 + 255) / 256, 256, 0, stream>>>(node_ids, emb, x0);
    prep_bn<<<1, 128, 0, stream>>>(c1_b1, c1_g, c1_be, c1_m, c1_v,
                                   c2_b1, c2_g, c2_be, c2_m, c2_v, ST);
    agg_kernel<64><<<(NN * 16 + 255) / 256, 256, 0, stream>>>(x0, rowstart, adj, agg1);
    layer_kernel<64, 128, true, true, true><<<(NN + 255) / 256, 256, 0, stream>>>(
        x0, agg1, c1_W1, nullptr, S1, T1, h1);
    layer_kernel<128, 128, false, false, true><<<(NN + 255) / 256, 256, 0, stream>>>(
        h1, h1, c1_W2, c1_b2, nullptr, nullptr, x1);

    // ---- conv2 ----
    agg_kernel<128><<<(NN * 32 + 255) / 256, 256, 0, stream>>>(x1, rowstart, adj, agg2);
    layer_kernel<128, 128, true, true, true><<<(NN + 255) / 256, 256, 0, stream>>>(
        x1, agg2, c2_W1, nullptr, S2, T2, h2);
    layer_kernel<128, 128, false, false, true><<<(NN + 255) / 256, 256, 0, stream>>>(
        h2, h2, c2_W2, c2_b2, nullptr, nullptr, x2);

    // ---- output projection ----
    layer_kernel<128, 64, false, false, false><<<(NN + 255) / 256, 256, 0, stream>>>(
        x2, x2, out_W, out_b, nullptr, nullptr, out);
}

// Round 14
// 803.931 us; speedup vs baseline: 6.0369x; 1.4688x over previous
//
#include <hip/hip_runtime.h>

#define NN 100000
#define EMBD 64
#define HIDD 128
#define OUTD 64
#define NE 1600000
#define BN_EPS 1e-5f
#define SCAN_B 1024
#define SCAN_NB ((NN + SCAN_B - 1) / SCAN_B)   // 98

// ---------------- gather: x0 = emb_table[node_ids] ----------------
__global__ void gather_kernel(const int* __restrict__ ids,
                              const float* __restrict__ emb,
                              float* __restrict__ x0) {
    int tid = blockIdx.x * 256 + threadIdx.x;       // NN*16 threads
    int i = tid >> 4, q = tid & 15;
    if (i >= NN) return;
    int nid = ids[i];
    float4 v = ((const float4*)(emb + (size_t)nid * EMBD))[q];
    ((float4*)(x0 + (size_t)i * EMBD))[q] = v;
}

// ---------------- CSR build ----------------
__global__ void hist_kernel(const int* __restrict__ dst, int* __restrict__ deg) {
    int e = blockIdx.x * 256 + threadIdx.x;
    if (e < NE) atomicAdd(&deg[dst[e]], 1);
}

__global__ void scan1_kernel(const int* __restrict__ deg, int* __restrict__ rowstart,
                             int* __restrict__ blocksum) {
    __shared__ int s[SCAN_B];
    int t = threadIdx.x, i = blockIdx.x * SCAN_B + t;
    int v = (i < NN) ? deg[i] : 0;
    s[t] = v;
    __syncthreads();
    for (int off = 1; off < SCAN_B; off <<= 1) {
        int a = (t >= off) ? s[t - off] : 0;
        __syncthreads();
        s[t] += a;
        __syncthreads();
    }
    if (i < NN) rowstart[i] = s[t] - v;              // exclusive within block
    if (t == SCAN_B - 1) blocksum[blockIdx.x] = s[t];
}

__global__ void scan2_kernel(int* __restrict__ blocksum) {
    if (threadIdx.x == 0 && blockIdx.x == 0) {
        int run = 0;
        for (int i = 0; i < SCAN_NB; ++i) { int t = blocksum[i]; blocksum[i] = run; run += t; }
    }
}

__global__ void scan3_kernel(int* __restrict__ rowstart, const int* __restrict__ blocksum,
                             int* __restrict__ cursor) {
    int t = threadIdx.x, i = blockIdx.x * SCAN_B + t;
    if (i < NN) {
        int r = rowstart[i] + blocksum[blockIdx.x];
        rowstart[i] = r;
        cursor[i] = r;
    }
    if (i == 0) rowstart[NN] = NE;
}

__global__ void fill_kernel(const int* __restrict__ src, const int* __restrict__ dst,
                            int* __restrict__ cursor, int* __restrict__ adj) {
    int e = blockIdx.x * 256 + threadIdx.x;
    if (e >= NE) return;
    int d = dst[e];
    int p = atomicAdd(&cursor[d], 1);
    adj[p] = src[e];
}

// ---------------- aggregate: agg[i] = sum_{j in adj[rs:re)} x[j], C channels ----------------
template<int C>
__global__ __launch_bounds__(256) void agg_kernel(const float* __restrict__ x,
                                                  const int* __restrict__ rowstart,
                                                  const int* __restrict__ adj,
                                                  float* __restrict__ agg) {
    constexpr int QP = C / 4;
    int tid = blockIdx.x * 256 + threadIdx.x;        // NN*QP threads
    int i = tid / QP, q = tid % QP;
    if (i >= NN) return;
    int rs = rowstart[i], re = rowstart[i + 1];
    float4 acc = {0.f, 0.f, 0.f, 0.f};
    for (int j = rs; j < re; ++j) {
        int s = adj[j];                              // broadcast within QP group
        float4 v = ((const float4*)(x + (size_t)s * C))[q];
        acc.x += v.x; acc.y += v.y; acc.z += v.z; acc.w += v.w;
    }
    ((float4*)(agg + (size_t)i * C))[q] = acc;
}

// ---------------- fold BN (+ linear bias) into per-channel scale/shift ----------------
__global__ void prep_bn(const float* __restrict__ c1_b1, const float* __restrict__ c1_g,
                        const float* __restrict__ c1_be, const float* __restrict__ c1_m,
                        const float* __restrict__ c1_v,
                        const float* __restrict__ c2_b1, const float* __restrict__ c2_g,
                        const float* __restrict__ c2_be, const float* __restrict__ c2_m,
                        const float* __restrict__ c2_v,
                        float* __restrict__ ST) {
    int t = threadIdx.x;                             // 128 threads
    float s1 = c1_g[t] * rsqrtf(c1_v[t] + BN_EPS);
    ST[t]       = s1;
    ST[128 + t] = (c1_b1[t] - c1_m[t]) * s1 + c1_be[t];
    float s2 = c2_g[t] * rsqrtf(c2_v[t] + BN_EPS);
    ST[256 + t] = s2;
    ST[384 + t] = (c2_b1[t] - c2_m[t]) * s2 + c2_be[t];
}

// ---------------- fused linear(+add)(+BN)(+ReLU): LDS-staged 64-node tiles ----------------
// Block = 256 threads handles TN=64 nodes. Stage A(+B) tile into LDS with fully
// coalesced float4 loads (fixes the 4x cache-line over-fetch of thread-per-node
// row reads: FETCH was 300-460MB vs ~103MB ideal at 194us, VALUBusy 13.9%).
// Compute: thread -> (node = t&63, channel-quarter g = t>>6). g is wave-uniform;
// readfirstlane pins it to an SGPR so W/S/T/bias loads stay s_load broadcasts.
// LDS row pad +4 floats keeps 16B alignment; 8-way bank conflict on reads is
// fine (ds_read ~35cy << 256cy of FMA issue per k4 step).
template<int IN, int OUT, bool ADD2, bool BN, bool RELU>
__global__ __launch_bounds__(256) void layer_kernel(
        const float* __restrict__ A, const float* __restrict__ B,
        const float* __restrict__ W, const float* __restrict__ bias,
        const float* __restrict__ S, const float* __restrict__ T,
        float* __restrict__ Y) {
    constexpr int TN = 64;
    constexpr int K4 = IN / 4;
    constexpr int CG = OUT / 4;
    __shared__ float Alds[TN][IN + 4];
    int base = blockIdx.x * TN;
    const float4* A4 = (const float4*)A;
    const float4* B4 = (const float4*)B;
    for (int f = threadIdx.x; f < TN * K4; f += 256) {
        int n = f / K4, k4 = f - n * K4;
        int gn = base + n;
        if (gn < NN) {
            float4 a = A4[(size_t)gn * K4 + k4];
            if constexpr (ADD2) {
                float4 b = B4[(size_t)gn * K4 + k4];
                a.x += b.x; a.y += b.y; a.z += b.z; a.w += b.w;
            }
            *(float4*)&Alds[n][k4 * 4] = a;
        }
    }
    __syncthreads();
    int t = threadIdx.x;
    int n = t & 63;
    int g = __builtin_amdgcn_readfirstlane(t >> 6);  // wave-uniform -> SGPR
    int gn = base + n;
    if (gn >= NN) return;
    float acc[CG];
#pragma unroll
    for (int j = 0; j < CG; ++j) acc[j] = 0.f;
    const float* Wg = W + g * CG;
    for (int k4 = 0; k4 < K4; ++k4) {
        float4 a = *(const float4*)&Alds[n][k4 * 4];
#pragma unroll
        for (int kk = 0; kk < 4; ++kk) {
            float xk = (kk == 0) ? a.x : (kk == 1) ? a.y : (kk == 2) ? a.z : a.w;
            const float* wrow = Wg + (size_t)(k4 * 4 + kk) * OUT;  // uniform -> s_load
#pragma unroll
            for (int j = 0; j < CG; ++j)
                acc[j] += xk * wrow[j];
        }
    }
    float* Yr = Y + (size_t)gn * OUT + g * CG;
#pragma unroll
    for (int j = 0; j < CG; ++j) {
        float y = acc[j];
        if constexpr (BN)  y = y * S[g * CG + j] + T[g * CG + j];
        else               y = y + bias[g * CG + j];
        if constexpr (RELU) y = fmaxf(y, 0.f);
        Yr[j] = y;
    }
}

extern "C" void kernel_launch(void* const* d_in, const int* in_sizes, int n_in,
                              void* d_out, int out_size, void* d_ws, size_t ws_size,
                              hipStream_t stream) {
    const int*   node_ids = (const int*)d_in[0];
    const int*   src      = (const int*)d_in[1];          // edge_index[0]
    const int*   dst      = ((const int*)d_in[1]) + NE;   // edge_index[1]
    const float* emb      = (const float*)d_in[2];
    const float* c1_W1 = (const float*)d_in[3];
    const float* c1_b1 = (const float*)d_in[4];
    const float* c1_g  = (const float*)d_in[5];
    const float* c1_be = (const float*)d_in[6];
    const float* c1_m  = (const float*)d_in[7];
    const float* c1_v  = (const float*)d_in[8];
    const float* c1_W2 = (const float*)d_in[9];
    const float* c1_b2 = (const float*)d_in[10];
    const float* c2_W1 = (const float*)d_in[11];
    const float* c2_b1 = (const float*)d_in[12];
    const float* c2_g  = (const float*)d_in[13];
    const float* c2_be = (const float*)d_in[14];
    const float* c2_m  = (const float*)d_in[15];
    const float* c2_v  = (const float*)d_in[16];
    const float* c2_W2 = (const float*)d_in[17];
    const float* c2_b2 = (const float*)d_in[18];
    const float* out_W = (const float*)d_in[19];
    const float* out_b = (const float*)d_in[20];
    float* out = (float*)d_out;

    // ---- workspace layout (4-byte words); peak footprint == proven 38.4M+512 ----
    float* ws = (float*)d_ws;
    const size_t W64  = (size_t)NN * 64;     // 6.4M
    const size_t W128 = (size_t)NN * 128;    // 12.8M
    float* x0   = ws;                        // [0, 6.4M)        live: gather..layer1
    float* agg1 = ws + W64;                  // [6.4M, 12.8M)    live: agg1..layer1
    float* h1   = ws + 2 * W64;              // [12.8M, 25.6M)   live: layer1..layer2
    float* x1   = ws;                        // [0, 12.8M)       live: layer2..layer3 (x0,agg1 dead)
    float* agg2 = ws + 2 * W64;              // [12.8M, 25.6M)   live: agg2..layer3 (h1 dead)
    float* h2   = ws + 2 * W64 + W128;       // [25.6M, 38.4M)   live: layer3..layer4
    float* x2   = ws;                        // [0, 12.8M)       live: layer4..out (x1 dead)
    // CSR block shares h2's region; CSR dead before h2 is written (layer3)
    int* rowstart = (int*)(ws + 2 * W64 + W128);       // NN+1 ints
    int* cursor   = rowstart + (NN + 1);               // NN ints (deg during hist)
    int* blocksum = cursor + NN;                       // SCAN_NB ints
    int* adj      = blocksum + 128;                    // NE ints  (total CSR ≈ 7.2 MB)
    float* ST = ws + 2 * W64 + 2 * W128;               // [38.4M, 38.4M+512)
    float* S1 = ST, *T1 = ST + 128, *S2 = ST + 256, *T2 = ST + 384;

    // ---- CSR build ----
    hipMemsetAsync(cursor, 0, NN * sizeof(int), stream);
    hist_kernel<<<(NE + 255) / 256, 256, 0, stream>>>(dst, cursor);
    scan1_kernel<<<SCAN_NB, SCAN_B, 0, stream>>>(cursor, rowstart, blocksum);
    scan2_kernel<<<1, 64, 0, stream>>>(blocksum);
    scan3_kernel<<<SCAN_NB, SCAN_B, 0, stream>>>(rowstart, blocksum, cursor);
    fill_kernel<<<(NE + 255) / 256, 256, 0, stream>>>(src, dst, cursor, adj);

    // ---- conv1 ----
    gather_kernel<<<(NN * 16 + 255) / 256, 256, 0, stream>>>(node_ids, emb, x0);
    prep_bn<<<1, 128, 0, stream>>>(c1_b1, c1_g, c1_be, c1_m, c1_v,
                                   c2_b1, c2_g, c2_be, c2_m, c2_v, ST);
    agg_kernel<64><<<(NN * 16 + 255) / 256, 256, 0, stream>>>(x0, rowstart, adj, agg1);
    layer_kernel<64, 128, true, true, true><<<(NN + 63) / 64, 256, 0, stream>>>(
        x0, agg1, c1_W1, nullptr, S1, T1, h1);
    layer_kernel<128, 128, false, false, true><<<(NN + 63) / 64, 256, 0, stream>>>(
        h1, h1, c1_W2, c1_b2, nullptr, nullptr, x1);

    // ---- conv2 ----
    agg_kernel<128><<<(NN * 32 + 255) / 256, 256, 0, stream>>>(x1, rowstart, adj, agg2);
    layer_kernel<128, 128, true, true, true><<<(NN + 63) / 64, 256, 0, stream>>>(
        x1, agg2, c2_W1, nullptr, S2, T2, h2);
    layer_kernel<128, 128, false, false, true><<<(NN + 63) / 64, 256, 0, stream>>>(
        h2, h2, c2_W2, c2_b2, nullptr, nullptr, x2);

    // ---- output projection ----
    layer_kernel<128, 64, false, false, false><<<(NN + 63) / 64, 256, 0, stream>>>(
        x2, x2, out_W, out_b, nullptr, nullptr, out);
}